// Round 4
// baseline (330.683 us; speedup 1.0000x reference)
//
#include <hip/hip_runtime.h>

#define CH   1024
#define NPTS 80
#define NEG  0.2f
#define INVTEMP 40.0f
#define NSLICE 4

typedef __attribute__((ext_vector_type(8))) short short8;
typedef __attribute__((ext_vector_type(4))) float f32x4;

// Split f32 into hi/lo bf16 (RNE). x ~= hi + lo with relative error ~2^-17.
__device__ __forceinline__ void bsplit(float x, short& hs, short& ls) {
  unsigned u = __builtin_bit_cast(unsigned, x);
  unsigned hb = (u + 0x7fffu + ((u >> 16) & 1u)) >> 16;
  float hf = __builtin_bit_cast(float, hb << 16);
  float r = x - hf;
  unsigned u2 = __builtin_bit_cast(unsigned, r);
  hs = (short)hb;
  ls = (short)((u2 + 0x7fffu + ((u2 >> 16) & 1u)) >> 16);
}

__device__ __forceinline__ float leaky(float v) { return v >= 0.f ? v : NEG * v; }

// ============================ Pipeline kernels ============================
// K1: partial Gram. grid = NSLICE*256, 256 thr (4 waves). Each block: 256
// channels of one batch -> G_part[slice][b][80][80] f32.
__launch_bounds__(256)
__global__ void k1_gram(const float* __restrict__ x, float* __restrict__ Gpart) {
  __shared__ float G[80][81];
  const int tid  = threadIdx.x;
  const int lane = tid & 63;
  const int wv   = tid >> 6;        // 0..3
  const int l15  = lane & 15;
  const int g    = lane >> 4;
  const int slice = blockIdx.x & (NSLICE - 1);
  const int b     = blockIdx.x >> 2;
  const float* __restrict__ xb = x + (size_t)b * (CH * NPTS);

  for (int i = tid; i < 80 * 81; i += 256) (&G[0][0])[i] = 0.f;

  f32x4 acc[5][5];
  #pragma unroll
  for (int i = 0; i < 5; ++i)
    #pragma unroll
    for (int j = 0; j < 5; ++j) acc[i][j] = (f32x4){0.f, 0.f, 0.f, 0.f};

  for (int ks2 = 0; ks2 < 2; ++ks2) {
    const int c0 = slice * 256 + wv * 64 + ks2 * 32 + g * 8;
    short8 fh[5], fl[5];
    #pragma unroll
    for (int t = 0; t < 5; ++t) {
      const int n = 16 * t + l15;
      #pragma unroll
      for (int j = 0; j < 8; ++j) {
        short hs, ls2;
        bsplit(xb[(c0 + j) * NPTS + n], hs, ls2);
        fh[t][j] = hs; fl[t][j] = ls2;
      }
    }
    #pragma unroll
    for (int tn = 0; tn < 5; ++tn)
      #pragma unroll
      for (int tm = 0; tm < 5; ++tm) {
        acc[tn][tm] = __builtin_amdgcn_mfma_f32_16x16x32_bf16(fh[tn], fh[tm], acc[tn][tm], 0, 0, 0);
        acc[tn][tm] = __builtin_amdgcn_mfma_f32_16x16x32_bf16(fh[tn], fl[tm], acc[tn][tm], 0, 0, 0);
        acc[tn][tm] = __builtin_amdgcn_mfma_f32_16x16x32_bf16(fl[tn], fh[tm], acc[tn][tm], 0, 0, 0);
      }
  }
  __syncthreads();
  #pragma unroll
  for (int tn = 0; tn < 5; ++tn)
    #pragma unroll
    for (int tm = 0; tm < 5; ++tm)
      #pragma unroll
      for (int r = 0; r < 4; ++r)
        atomicAdd(&G[16 * tn + 4 * g + r][16 * tm + l15], acc[tn][tm][r]);
  __syncthreads();

  float* __restrict__ gp = Gpart + ((size_t)slice * 256 + b) * 6400;
  for (int i = tid; i < 6400; i += 256) gp[i] = G[i / 80][i % 80];
}

// K2: sum partials, normalize -> adj bf16 hi/lo (stride 96, zero-padded),
// zero the score accumulator. grid = 256.
__launch_bounds__(256)
__global__ void k2_adj(const float* __restrict__ Gpart,
                       unsigned short* __restrict__ adjh,
                       unsigned short* __restrict__ adjl,
                       float* __restrict__ s) {
  __shared__ float Gs[80][80];
  __shared__ float rn[80];
  const int tid = threadIdx.x;
  const int b = blockIdx.x;
  if (tid < 80) s[b * 80 + tid] = 0.f;
  for (int i = tid; i < 6400; i += 256) {
    float v = 0.f;
    #pragma unroll
    for (int sl = 0; sl < NSLICE; ++sl)
      v += Gpart[((size_t)sl * 256 + b) * 6400 + i];
    (&Gs[0][0])[i] = v;
  }
  __syncthreads();
  if (tid < 80) rn[tid] = 1.0f / fmaxf(sqrtf(Gs[tid][tid]), 1e-12f);
  __syncthreads();
  for (int i = tid; i < 80 * 96; i += 256) {
    const int m = i / 96;
    const int n = i - m * 96;
    float v = (n < 80) ? Gs[m][n] * (rn[m] * rn[n]) : 0.f;
    short hs, ls2; bsplit(v, hs, ls2);
    adjh[(size_t)b * 7680 + i] = (unsigned short)hs;
    adjl[(size_t)b * 7680 + i] = (unsigned short)ls2;
  }
}

// K3: h = X @ adj fused leaky + w-reduce. grid = NSLICE*256 (channel slices),
// 256 thr. atomicAdd partial scores into s[b][n].
__launch_bounds__(256)
__global__ void k3_gemm2(const float* __restrict__ x,
                         const unsigned short* __restrict__ adjh_g,
                         const unsigned short* __restrict__ adjl_g,
                         const float* __restrict__ w,
                         float* __restrict__ s) {
  __shared__ __align__(16) short adjh[80][104];
  __shared__ __align__(16) short adjl[80][104];
  __shared__ float wl[256];
  __shared__ float ssc[80];
  const int tid  = threadIdx.x;
  const int lane = tid & 63;
  const int wv   = tid >> 6;        // 0..3
  const int l15  = lane & 15;
  const int g    = lane >> 4;
  const int slice = blockIdx.x & (NSLICE - 1);
  const int b     = blockIdx.x >> 2;
  const float* __restrict__ xb = x + (size_t)b * (CH * NPTS);

  for (int i = tid; i < 960; i += 256) {           // 80*96/8 short8 units
    const int row = i / 12;
    const int c8  = (i - row * 12) * 8;
    short8 vh = *reinterpret_cast<const short8*>(adjh_g + (size_t)b * 7680 + row * 96 + c8);
    short8 vl = *reinterpret_cast<const short8*>(adjl_g + (size_t)b * 7680 + row * 96 + c8);
    *reinterpret_cast<short8*>(&adjh[row][c8]) = vh;
    *reinterpret_cast<short8*>(&adjl[row][c8]) = vl;
  }
  wl[tid] = w[slice * 256 + tid];
  if (tid < 80) ssc[tid] = 0.f;
  __syncthreads();

  f32x4 hacc[4][5];
  #pragma unroll
  for (int i = 0; i < 4; ++i)
    #pragma unroll
    for (int j = 0; j < 5; ++j) hacc[i][j] = (f32x4){0.f, 0.f, 0.f, 0.f};

  for (int ksn = 0; ksn < 3; ++ksn) {
    const int nb = 32 * ksn + 8 * g;
    short8 bh[5], bl[5];
    #pragma unroll
    for (int tm = 0; tm < 5; ++tm) {
      bh[tm] = *reinterpret_cast<const short8*>(&adjh[16 * tm + l15][nb]);
      bl[tm] = *reinterpret_cast<const short8*>(&adjl[16 * tm + l15][nb]);
    }
    #pragma unroll
    for (int t4 = 0; t4 < 4; ++t4) {
      const int row = slice * 256 + wv * 64 + t4 * 16 + l15;
      short8 ah, al;
      if (nb < 80) {
        const float* p = xb + row * NPTS + nb;
        f32x4 va = *reinterpret_cast<const f32x4*>(p);
        f32x4 vb = *reinterpret_cast<const f32x4*>(p + 4);
        #pragma unroll
        for (int j = 0; j < 4; ++j) { short hs, ls2; bsplit(va[j], hs, ls2); ah[j] = hs; al[j] = ls2; }
        #pragma unroll
        for (int j = 0; j < 4; ++j) { short hs, ls2; bsplit(vb[j], hs, ls2); ah[4 + j] = hs; al[4 + j] = ls2; }
      } else {
        ah = (short8){0,0,0,0,0,0,0,0};
        al = (short8){0,0,0,0,0,0,0,0};
      }
      #pragma unroll
      for (int tm = 0; tm < 5; ++tm) {
        hacc[t4][tm] = __builtin_amdgcn_mfma_f32_16x16x32_bf16(ah, bh[tm], hacc[t4][tm], 0, 0, 0);
        hacc[t4][tm] = __builtin_amdgcn_mfma_f32_16x16x32_bf16(ah, bl[tm], hacc[t4][tm], 0, 0, 0);
        hacc[t4][tm] = __builtin_amdgcn_mfma_f32_16x16x32_bf16(al, bh[tm], hacc[t4][tm], 0, 0, 0);
      }
    }
  }

  float sp[5] = {0.f, 0.f, 0.f, 0.f, 0.f};
  #pragma unroll
  for (int t4 = 0; t4 < 4; ++t4) {
    const int cbl = wv * 64 + t4 * 16 + 4 * g;
    #pragma unroll
    for (int r = 0; r < 4; ++r) {
      const float wc = wl[cbl + r];
      #pragma unroll
      for (int tm = 0; tm < 5; ++tm) sp[tm] += leaky(hacc[t4][tm][r]) * wc;
    }
  }
  #pragma unroll
  for (int tm = 0; tm < 5; ++tm) {
    float v = sp[tm];
    v += __shfl_xor(v, 16);
    v += __shfl_xor(v, 32);
    if (g == 0) atomicAdd(&ssc[16 * tm + l15], v);
  }
  __syncthreads();
  if (tid < 80) atomicAdd(&s[b * 80 + tid], ssc[tid]);
}

// K5: per-block redundant softmax + streaming scale. grid = 256*10.
__launch_bounds__(256)
__global__ void k5_scale(const float* __restrict__ x,
                         const float* __restrict__ s,
                         const float* __restrict__ bias,
                         float* __restrict__ out) {
  __shared__ float att[80];
  __shared__ f32x4 attnv[20];
  const int tid = threadIdx.x;
  const int b = blockIdx.x / 10;
  const int chunk = blockIdx.x - b * 10;

  if (tid < 64) {
    const int lane = tid;
    const float b0 = bias[0];
    float v0 = leaky(s[b * 80 + lane] + b0) * INVTEMP;
    float v1 = -3.0e38f;
    if (lane < 16) v1 = leaky(s[b * 80 + 64 + lane] + b0) * INVTEMP;
    float mx = fmaxf(v0, v1);
    #pragma unroll
    for (int off = 32; off >= 1; off >>= 1) mx = fmaxf(mx, __shfl_xor(mx, off));
    float e0 = expf(v0 - mx);
    float e1 = (lane < 16) ? expf(v1 - mx) : 0.f;
    float sum = e0 + e1;
    #pragma unroll
    for (int off = 32; off >= 1; off >>= 1) sum += __shfl_xor(sum, off);
    const float inv = 1.0f / sum;
    att[lane] = e0 * inv + 1.0f;
    if (lane < 16) att[64 + lane] = e1 * inv + 1.0f;
  }
  __syncthreads();
  if (tid < 20) {
    f32x4 a = { att[4 * tid], att[4 * tid + 1], att[4 * tid + 2], att[4 * tid + 3] };
    attnv[tid] = a;
  }
  __syncthreads();

  const f32x4* __restrict__ xv = reinterpret_cast<const f32x4*>(x + (size_t)b * (CH * NPTS));
  f32x4* __restrict__ ov = reinterpret_cast<f32x4*>(out + (size_t)b * (CH * NPTS));
  #pragma unroll
  for (int k = 0; k < 8; ++k) {
    const int e4 = chunk * 2048 + k * 256 + tid;    // f32x4 index in batch
    f32x4 v = xv[e4];
    f32x4 a = attnv[e4 % 20];
    v[0] *= a[0]; v[1] *= a[1]; v[2] *= a[2]; v[3] *= a[3];
    ov[e4] = v;
  }
}

// ==================== Fallback: proven fused single kernel ====================
__launch_bounds__(512, 1)
__global__ void scgcn_fused_kernel(const float* __restrict__ x,
                                   const float* __restrict__ w,
                                   const float* __restrict__ bias,
                                   float* __restrict__ out) {
  __shared__ float G[80][81];
  __shared__ float rn[80];
  __shared__ float ssc[80];
  __shared__ float wl[CH];
  __shared__ __align__(16) short adjh[80][104];
  __shared__ __align__(16) short adjl[80][104];
  __shared__ f32x4 attnv[20];

  const int tid  = threadIdx.x;
  const int lane = tid & 63;
  const int wv   = tid >> 6;
  const int l15  = lane & 15;
  const int g    = lane >> 4;
  const int b    = blockIdx.x;
  const float* __restrict__ xb = x + (size_t)b * (CH * NPTS);

  for (int i = tid; i < 80 * 81; i += 512) (&G[0][0])[i] = 0.f;
  if (tid < 80) ssc[tid] = 0.f;
  for (int i = tid; i < CH; i += 512) wl[i] = w[i];

  f32x4 acc[5][5];
  #pragma unroll
  for (int i = 0; i < 5; ++i)
    #pragma unroll
    for (int j = 0; j < 5; ++j) acc[i][j] = (f32x4){0.f, 0.f, 0.f, 0.f};

  for (int ks = 0; ks < 4; ++ks) {
    const int c0 = wv * 128 + ks * 32 + g * 8;
    short8 fh[5], fl[5];
    #pragma unroll
    for (int t = 0; t < 5; ++t) {
      const int n = 16 * t + l15;
      #pragma unroll
      for (int j = 0; j < 8; ++j) {
        short hs, ls2;
        bsplit(xb[(c0 + j) * NPTS + n], hs, ls2);
        fh[t][j] = hs; fl[t][j] = ls2;
      }
    }
    #pragma unroll
    for (int tn = 0; tn < 5; ++tn)
      #pragma unroll
      for (int tm = 0; tm < 5; ++tm) {
        acc[tn][tm] = __builtin_amdgcn_mfma_f32_16x16x32_bf16(fh[tn], fh[tm], acc[tn][tm], 0, 0, 0);
        acc[tn][tm] = __builtin_amdgcn_mfma_f32_16x16x32_bf16(fh[tn], fl[tm], acc[tn][tm], 0, 0, 0);
        acc[tn][tm] = __builtin_amdgcn_mfma_f32_16x16x32_bf16(fl[tn], fh[tm], acc[tn][tm], 0, 0, 0);
      }
  }
  __syncthreads();
  #pragma unroll
  for (int tn = 0; tn < 5; ++tn)
    #pragma unroll
    for (int tm = 0; tm < 5; ++tm)
      #pragma unroll
      for (int r = 0; r < 4; ++r)
        atomicAdd(&G[16 * tn + 4 * g + r][16 * tm + l15], acc[tn][tm][r]);
  __syncthreads();

  if (tid < 80) rn[tid] = 1.0f / fmaxf(sqrtf(G[tid][tid]), 1e-12f);
  __syncthreads();
  for (int i = tid; i < 80 * 104; i += 512) {
    const int m = i / 104;
    const int n = i - m * 104;
    float v = (n < 80) ? G[n][m] * (rn[n] * rn[m]) : 0.f;
    short hs, ls2; bsplit(v, hs, ls2);
    adjh[m][n] = hs; adjl[m][n] = ls2;
  }
  __syncthreads();

  float sp[5] = {0.f, 0.f, 0.f, 0.f, 0.f};
  for (int chunk = 0; chunk < 2; ++chunk) {
    f32x4 hacc[4][5];
    #pragma unroll
    for (int i = 0; i < 4; ++i)
      #pragma unroll
      for (int j = 0; j < 5; ++j) hacc[i][j] = (f32x4){0.f, 0.f, 0.f, 0.f};

    for (int ksn = 0; ksn < 3; ++ksn) {
      const int nb = 32 * ksn + 8 * g;
      short8 bh[5], bl[5];
      #pragma unroll
      for (int tm = 0; tm < 5; ++tm) {
        bh[tm] = *reinterpret_cast<const short8*>(&adjh[16 * tm + l15][nb]);
        bl[tm] = *reinterpret_cast<const short8*>(&adjl[16 * tm + l15][nb]);
      }
      #pragma unroll
      for (int t4 = 0; t4 < 4; ++t4) {
        const int ct = wv * 8 + chunk * 4 + t4;
        short8 ah, al;
        if (nb < 80) {
          const float* p = xb + (16 * ct + l15) * NPTS + nb;
          f32x4 va = *reinterpret_cast<const f32x4*>(p);
          f32x4 vb = *reinterpret_cast<const f32x4*>(p + 4);
          #pragma unroll
          for (int j = 0; j < 4; ++j) { short hs, ls2; bsplit(va[j], hs, ls2); ah[j] = hs; al[j] = ls2; }
          #pragma unroll
          for (int j = 0; j < 4; ++j) { short hs, ls2; bsplit(vb[j], hs, ls2); ah[4 + j] = hs; al[4 + j] = ls2; }
        } else {
          ah = (short8){0,0,0,0,0,0,0,0};
          al = (short8){0,0,0,0,0,0,0,0};
        }
        #pragma unroll
        for (int tm = 0; tm < 5; ++tm) {
          hacc[t4][tm] = __builtin_amdgcn_mfma_f32_16x16x32_bf16(ah, bh[tm], hacc[t4][tm], 0, 0, 0);
          hacc[t4][tm] = __builtin_amdgcn_mfma_f32_16x16x32_bf16(ah, bl[tm], hacc[t4][tm], 0, 0, 0);
          hacc[t4][tm] = __builtin_amdgcn_mfma_f32_16x16x32_bf16(al, bh[tm], hacc[t4][tm], 0, 0, 0);
        }
      }
    }
    #pragma unroll
    for (int t4 = 0; t4 < 4; ++t4) {
      const int cb = 16 * (wv * 8 + chunk * 4 + t4) + 4 * g;
      #pragma unroll
      for (int r = 0; r < 4; ++r) {
        const float wc = wl[cb + r];
        #pragma unroll
        for (int tm = 0; tm < 5; ++tm) sp[tm] += leaky(hacc[t4][tm][r]) * wc;
      }
    }
  }
  #pragma unroll
  for (int tm = 0; tm < 5; ++tm) {
    float v = sp[tm];
    v += __shfl_xor(v, 16);
    v += __shfl_xor(v, 32);
    if (g == 0) atomicAdd(&ssc[16 * tm + l15], v);
  }
  __syncthreads();

  if (wv == 0) {
    const float b0 = bias[0];
    float v0 = leaky(ssc[lane] + b0) * INVTEMP;
    float v1 = -3.0e38f;
    if (lane < 16) v1 = leaky(ssc[64 + lane] + b0) * INVTEMP;
    float mx = fmaxf(v0, v1);
    #pragma unroll
    for (int off = 32; off >= 1; off >>= 1) mx = fmaxf(mx, __shfl_xor(mx, off));
    float e0 = expf(v0 - mx);
    float e1 = (lane < 16) ? expf(v1 - mx) : 0.f;
    float sum = e0 + e1;
    #pragma unroll
    for (int off = 32; off >= 1; off >>= 1) sum += __shfl_xor(sum, off);
    const float inv = 1.0f / sum;
    ssc[lane] = e0 * inv + 1.0f;
    if (lane < 16) ssc[64 + lane] = e1 * inv + 1.0f;
  }
  __syncthreads();
  if (tid < 20) {
    f32x4 a = { ssc[4 * tid], ssc[4 * tid + 1], ssc[4 * tid + 2], ssc[4 * tid + 3] };
    attnv[tid] = a;
  }
  __syncthreads();

  float* __restrict__ ob = out + (size_t)b * (CH * NPTS);
  const f32x4* xv = reinterpret_cast<const f32x4*>(xb);
  f32x4* ov = reinterpret_cast<f32x4*>(ob);
  #pragma unroll 4
  for (int i = tid; i < (CH * NPTS) / 4; i += 512) {
    f32x4 v = xv[i];
    f32x4 a = attnv[i % 20];
    v[0] *= a[0]; v[1] *= a[1]; v[2] *= a[2]; v[3] *= a[3];
    ov[i] = v;
  }
}

extern "C" void kernel_launch(void* const* d_in, const int* in_sizes, int n_in,
                              void* d_out, int out_size, void* d_ws, size_t ws_size,
                              hipStream_t stream) {
  const float* x    = (const float*)d_in[0];
  const float* w    = (const float*)d_in[1];
  const float* bias = (const float*)d_in[2];
  float* out        = (float*)d_out;

  const size_t gpart_bytes = (size_t)NSLICE * 256 * 6400 * sizeof(float);   // 26.2 MB
  const size_t adj_bytes   = (size_t)256 * 7680 * sizeof(unsigned short);   // 3.93 MB each
  const size_t s_bytes     = (size_t)256 * 80 * sizeof(float);
  const size_t need = gpart_bytes + 2 * adj_bytes + s_bytes;

  if (ws_size >= need) {
    char* p = (char*)d_ws;
    float* Gpart = (float*)p;                 p += gpart_bytes;
    unsigned short* adjh = (unsigned short*)p; p += adj_bytes;
    unsigned short* adjl = (unsigned short*)p; p += adj_bytes;
    float* sws = (float*)p;

    k1_gram<<<NSLICE * 256, 256, 0, stream>>>(x, Gpart);
    k2_adj<<<256, 256, 0, stream>>>(Gpart, adjh, adjl, sws);
    k3_gemm2<<<NSLICE * 256, 256, 0, stream>>>(x, adjh, adjl, w, sws);
    k5_scale<<<256 * 10, 256, 0, stream>>>(x, sws, bias, out);
  } else {
    scgcn_fused_kernel<<<256, 512, 0, stream>>>(x, w, bias, out);
  }
}

// Round 5
// 274.890 us; speedup vs baseline: 1.2030x; 1.2030x over previous
//
#include <hip/hip_runtime.h>

#define CH   1024
#define NPTS 80
#define NEG  0.2f
#define INVTEMP 40.0f

typedef __attribute__((ext_vector_type(8))) short short8;
typedef __attribute__((ext_vector_type(4))) float f32x4;
typedef __attribute__((ext_vector_type(4))) unsigned u32x4;

// Split f32 into hi/lo bf16 (RNE). x ~= hi + lo with relative error ~2^-17.
__device__ __forceinline__ void bsplit(float x, short& hs, short& ls) {
  unsigned u = __builtin_bit_cast(unsigned, x);
  unsigned hb = (u + 0x7fffu + ((u >> 16) & 1u)) >> 16;
  float hf = __builtin_bit_cast(float, hb << 16);
  float r = x - hf;
  unsigned u2 = __builtin_bit_cast(unsigned, r);
  hs = (short)hb;
  ls = (short)((u2 + 0x7fffu + ((u2 >> 16) & 1u)) >> 16);
}

__device__ __forceinline__ unsigned packhl(float x) {
  short hs, ls; bsplit(x, hs, ls);
  return ((unsigned)(unsigned short)hs << 16) | (unsigned)(unsigned short)ls;
}

// q0 = packed channels c..c+3, q1 = c+4..c+7 (each u32 = hi<<16 | lo)
__device__ __forceinline__ void unpack8(u32x4 q0, u32x4 q1, short8& fh, short8& fl) {
  union { unsigned u[4]; short8 s; } a, b;
  a.u[0] = (q0[0] >> 16) | (q0[1] & 0xffff0000u);
  a.u[1] = (q0[2] >> 16) | (q0[3] & 0xffff0000u);
  a.u[2] = (q1[0] >> 16) | (q1[1] & 0xffff0000u);
  a.u[3] = (q1[2] >> 16) | (q1[3] & 0xffff0000u);
  b.u[0] = (q0[0] & 0xffffu) | (q0[1] << 16);
  b.u[1] = (q0[2] & 0xffffu) | (q0[3] << 16);
  b.u[2] = (q1[0] & 0xffffu) | (q1[1] << 16);
  b.u[3] = (q1[2] & 0xffffu) | (q1[3] << 16);
  fh = a.s; fl = b.s;
}

__device__ __forceinline__ float leaky(float v) { return v >= 0.f ? v : NEG * v; }

// One block per batch, 512 threads = 8 waves.
// Phase 1: Gram via LDS-staged x (4 chunks x 256 ch). Stage: coalesced global
//   dword loads -> bsplit -> packed u32 (hi|lo) -> xP[n][c] (stride 260) via
//   ds_write_b128. Frags: 2x ds_read_b128 + unpack. Wave wv owns k-slice
//   [wv*32, wv*32+32) of each chunk; acc merged via LDS atomics at end.
// Phase 2: adj = G/(norm n norm m) -> bf16 hi/lo LDS (overlays xP).
// Phase 3: h = X @ adj fused leaky + w-reduce (global 32B loads, as proven).
// Phase 4: softmax*40 + 1.  Phase 5: out = x * attn.
__launch_bounds__(512, 1)
__global__ void scgcn_fused_kernel(const float* __restrict__ x,
                                   const float* __restrict__ w,
                                   const float* __restrict__ bias,
                                   float* __restrict__ out) {
  __shared__ __align__(16) char smem[83200];     // xP[80][260] u32  OR adj h/l
  __shared__ float G[80][81];
  __shared__ float rn[80];
  __shared__ float ssc[80];
  __shared__ float wl[CH];
  __shared__ f32x4 attnv[20];

  unsigned* __restrict__ xP = (unsigned*)smem;                  // [80][260]
  short (*adjh)[104] = (short (*)[104])smem;                    // 16640 B
  short (*adjl)[104] = (short (*)[104])(smem + 16640);          // 16640 B

  const int tid  = threadIdx.x;
  const int lane = tid & 63;
  const int wv   = tid >> 6;        // wave 0..7
  const int l15  = lane & 15;
  const int g    = lane >> 4;       // 0..3
  const int b    = blockIdx.x;
  const float* __restrict__ xb = x + (size_t)b * (CH * NPTS);

  // ---- init LDS ----
  for (int i = tid; i < 80 * 81; i += 512) (&G[0][0])[i] = 0.f;
  if (tid < 80) ssc[tid] = 0.f;
  for (int i = tid; i < CH; i += 512) wl[i] = w[i];

  // ---- Phase 1: Gram over 4 chunks of 256 channels ----
  f32x4 acc[5][5];
  #pragma unroll
  for (int i = 0; i < 5; ++i)
    #pragma unroll
    for (int j = 0; j < 5; ++j) acc[i][j] = (f32x4){0.f, 0.f, 0.f, 0.f};

  for (int chunk = 0; chunk < 4; ++chunk) {
    // stage: 10 units/thread; unit = (c0 = 4*(U/80), n = U%80)
    for (int k = 0; k < 10; ++k) {
      const int U  = tid + 512 * k;
      const int n  = U % 80;
      const int c0 = (U / 80) * 4;
      const float* p = xb + (size_t)(chunk * 256 + c0) * NPTS + n;
      u32x4 pk;
      pk[0] = packhl(p[0 * NPTS]);
      pk[1] = packhl(p[1 * NPTS]);
      pk[2] = packhl(p[2 * NPTS]);
      pk[3] = packhl(p[3 * NPTS]);
      *reinterpret_cast<u32x4*>(&xP[n * 260 + c0]) = pk;
    }
    __syncthreads();   // staging visible

    // fragment reads: wave wv covers channels [wv*32, wv*32+32) of chunk
    short8 fh[5], fl[5];
    const int cbase = wv * 32 + g * 8;
    #pragma unroll
    for (int t = 0; t < 5; ++t) {
      const int n = 16 * t + l15;
      u32x4 q0 = *reinterpret_cast<const u32x4*>(&xP[n * 260 + cbase]);
      u32x4 q1 = *reinterpret_cast<const u32x4*>(&xP[n * 260 + cbase + 4]);
      unpack8(q0, q1, fh[t], fl[t]);
    }
    __syncthreads();   // all reads done; safe to overwrite next chunk

    #pragma unroll
    for (int tn = 0; tn < 5; ++tn)
      #pragma unroll
      for (int tm = 0; tm < 5; ++tm) {
        acc[tn][tm] = __builtin_amdgcn_mfma_f32_16x16x32_bf16(fh[tn], fh[tm], acc[tn][tm], 0, 0, 0);
        acc[tn][tm] = __builtin_amdgcn_mfma_f32_16x16x32_bf16(fh[tn], fl[tm], acc[tn][tm], 0, 0, 0);
        acc[tn][tm] = __builtin_amdgcn_mfma_f32_16x16x32_bf16(fl[tn], fh[tm], acc[tn][tm], 0, 0, 0);
      }
  }

  __syncthreads();
  #pragma unroll
  for (int tn = 0; tn < 5; ++tn)
    #pragma unroll
    for (int tm = 0; tm < 5; ++tm)
      #pragma unroll
      for (int r = 0; r < 4; ++r)
        atomicAdd(&G[16 * tn + 4 * g + r][16 * tm + l15], acc[tn][tm][r]);
  __syncthreads();

  // ---- Phase 2: adj -> bf16 hi/lo (overlays xP; xP dead) ----
  if (tid < 80) rn[tid] = 1.0f / fmaxf(sqrtf(G[tid][tid]), 1e-12f);
  __syncthreads();
  for (int i = tid; i < 80 * 104; i += 512) {
    const int m = i / 104;
    const int n = i - m * 104;
    float v = (n < 80) ? G[n][m] * (rn[n] * rn[m]) : 0.f;
    short hs, ls2; bsplit(v, hs, ls2);
    adjh[m][n] = hs; adjl[m][n] = ls2;
  }
  __syncthreads();

  // ---- Phase 3: h = X @ adj, fused leaky + w-reduce ----
  float sp[5] = {0.f, 0.f, 0.f, 0.f, 0.f};
  for (int chunk = 0; chunk < 2; ++chunk) {
    f32x4 hacc[4][5];
    #pragma unroll
    for (int i = 0; i < 4; ++i)
      #pragma unroll
      for (int j = 0; j < 5; ++j) hacc[i][j] = (f32x4){0.f, 0.f, 0.f, 0.f};

    for (int ksn = 0; ksn < 3; ++ksn) {
      const int nb = 32 * ksn + 8 * g;
      short8 bh[5], bl[5];
      #pragma unroll
      for (int tm = 0; tm < 5; ++tm) {
        bh[tm] = *reinterpret_cast<const short8*>(&adjh[16 * tm + l15][nb]);
        bl[tm] = *reinterpret_cast<const short8*>(&adjl[16 * tm + l15][nb]);
      }
      #pragma unroll
      for (int t4 = 0; t4 < 4; ++t4) {
        const int ct = wv * 8 + chunk * 4 + t4;
        short8 ah, al;
        if (nb < 80) {
          const float* p = xb + (16 * ct + l15) * NPTS + nb;
          f32x4 va = *reinterpret_cast<const f32x4*>(p);
          f32x4 vb = *reinterpret_cast<const f32x4*>(p + 4);
          #pragma unroll
          for (int j = 0; j < 4; ++j) { short hs, ls2; bsplit(va[j], hs, ls2); ah[j] = hs; al[j] = ls2; }
          #pragma unroll
          for (int j = 0; j < 4; ++j) { short hs, ls2; bsplit(vb[j], hs, ls2); ah[4 + j] = hs; al[4 + j] = ls2; }
        } else {
          ah = (short8){0,0,0,0,0,0,0,0};
          al = (short8){0,0,0,0,0,0,0,0};
        }
        #pragma unroll
        for (int tm = 0; tm < 5; ++tm) {
          hacc[t4][tm] = __builtin_amdgcn_mfma_f32_16x16x32_bf16(ah, bh[tm], hacc[t4][tm], 0, 0, 0);
          hacc[t4][tm] = __builtin_amdgcn_mfma_f32_16x16x32_bf16(ah, bl[tm], hacc[t4][tm], 0, 0, 0);
          hacc[t4][tm] = __builtin_amdgcn_mfma_f32_16x16x32_bf16(al, bh[tm], hacc[t4][tm], 0, 0, 0);
        }
      }
    }
    #pragma unroll
    for (int t4 = 0; t4 < 4; ++t4) {
      const int cb = 16 * (wv * 8 + chunk * 4 + t4) + 4 * g;
      #pragma unroll
      for (int r = 0; r < 4; ++r) {
        const float wc = wl[cb + r];
        #pragma unroll
        for (int tm = 0; tm < 5; ++tm) sp[tm] += leaky(hacc[t4][tm][r]) * wc;
      }
    }
  }
  #pragma unroll
  for (int tm = 0; tm < 5; ++tm) {
    float v = sp[tm];
    v += __shfl_xor(v, 16);
    v += __shfl_xor(v, 32);
    if (g == 0) atomicAdd(&ssc[16 * tm + l15], v);
  }
  __syncthreads();

  // ---- Phase 4: softmax (wave 0 only) ----
  if (wv == 0) {
    const float b0 = bias[0];
    float v0 = leaky(ssc[lane] + b0) * INVTEMP;
    float v1 = -3.0e38f;
    if (lane < 16) v1 = leaky(ssc[64 + lane] + b0) * INVTEMP;
    float mx = fmaxf(v0, v1);
    #pragma unroll
    for (int off = 32; off >= 1; off >>= 1) mx = fmaxf(mx, __shfl_xor(mx, off));
    float e0 = expf(v0 - mx);
    float e1 = (lane < 16) ? expf(v1 - mx) : 0.f;
    float sum = e0 + e1;
    #pragma unroll
    for (int off = 32; off >= 1; off >>= 1) sum += __shfl_xor(sum, off);
    const float inv = 1.0f / sum;
    ssc[lane] = e0 * inv + 1.0f;
    if (lane < 16) ssc[64 + lane] = e1 * inv + 1.0f;
  }
  __syncthreads();
  if (tid < 20) {
    f32x4 a = { ssc[4 * tid], ssc[4 * tid + 1], ssc[4 * tid + 2], ssc[4 * tid + 3] };
    attnv[tid] = a;
  }
  __syncthreads();

  // ---- Phase 5: out = x * attn[n] ----
  float* __restrict__ ob = out + (size_t)b * (CH * NPTS);
  const f32x4* xv = reinterpret_cast<const f32x4*>(xb);
  f32x4* ov = reinterpret_cast<f32x4*>(ob);
  #pragma unroll 4
  for (int i = tid; i < (CH * NPTS) / 4; i += 512) {
    f32x4 v = xv[i];
    f32x4 a = attnv[i % 20];
    v[0] *= a[0]; v[1] *= a[1]; v[2] *= a[2]; v[3] *= a[3];
    ov[i] = v;
  }
}

extern "C" void kernel_launch(void* const* d_in, const int* in_sizes, int n_in,
                              void* d_out, int out_size, void* d_ws, size_t ws_size,
                              hipStream_t stream) {
  const float* x    = (const float*)d_in[0];
  const float* w    = (const float*)d_in[1];
  const float* bias = (const float*)d_in[2];
  float* out        = (float*)d_out;
  scgcn_fused_kernel<<<256, 512, 0, stream>>>(x, w, bias, out);
}

// Round 10
// 252.299 us; speedup vs baseline: 1.3107x; 1.0895x over previous
//
#include <hip/hip_runtime.h>

#define CH   1024
#define NPTS 80
#define NEG  0.2f
#define INVTEMP 40.0f

typedef __attribute__((ext_vector_type(8))) short short8;
typedef __attribute__((ext_vector_type(4))) float f32x4;

// Split f32 into hi/lo bf16 (RNE). x ~= hi + lo with relative error ~2^-17.
__device__ __forceinline__ void bsplit(float x, short& hs, short& ls) {
  unsigned u = __builtin_bit_cast(unsigned, x);
  unsigned hb = (u + 0x7fffu + ((u >> 16) & 1u)) >> 16;
  float hf = __builtin_bit_cast(float, hb << 16);
  float r = x - hf;
  unsigned u2 = __builtin_bit_cast(unsigned, r);
  hs = (short)hb;
  ls = (short)((u2 + 0x7fffu + ((u2 >> 16) & 1u)) >> 16);
}

__device__ __forceinline__ float leaky(float v) { return v >= 0.f ? v : NEG * v; }

// Async global->LDS DMA, 16 B per lane. LDS dest must be wave-uniform base
// (HW adds lane*16); global src is per-lane.
__device__ __forceinline__ void dma16(const void* g, void* l) {
  __builtin_amdgcn_global_load_lds(
      (const __attribute__((address_space(1))) unsigned*)g,
      (__attribute__((address_space(3))) unsigned*)l,
      16, 0, 0);
}

// Main kernel: one block per batch, 512 threads = 8 waves. Phases 1-4.
// Phase 1: Gram. 4 chunks of 256 ch staged to LDS via global_load_lds
//   (80 KB linear [c][80] f32). Wave wv owns k-slice [wv*32,wv*32+32);
//   frags via ds_read + bsplit; acc merged via LDS atomics.
// Phase 2: adj = G/(nn*nm) -> bf16 hi/lo [m][104] in LDS.
// Phase 3: h = X @ adj fused leaky+w-reduce; same DMA staging.
// Phase 4: softmax*40+1 -> attn_ws[b][80]  (scale pass is a separate kernel).
__launch_bounds__(512, 1)
__global__ void scgcn_main_kernel(const float* __restrict__ x,
                                  const float* __restrict__ w,
                                  const float* __restrict__ bias,
                                  float* __restrict__ attn_ws) {
  __shared__ __align__(16) float xstage[256 * 80];   // 80 KB staged chunk
  __shared__ float G[80][81];
  __shared__ float rn[80];
  __shared__ float ssc[80];
  __shared__ float wl[CH];
  __shared__ __align__(16) short adjh[80][104];
  __shared__ __align__(16) short adjl[80][104];

  const int tid  = threadIdx.x;
  const int lane = tid & 63;
  const int wv   = tid >> 6;        // wave 0..7
  const int l15  = lane & 15;
  const int g    = lane >> 4;       // 0..3
  const int b    = blockIdx.x;
  const float* __restrict__ xb = x + (size_t)b * (CH * NPTS);

  // ---- init LDS ----
  for (int i = tid; i < 80 * 81; i += 512) (&G[0][0])[i] = 0.f;
  if (tid < 80) ssc[tid] = 0.f;
  for (int i = tid; i < CH; i += 512) wl[i] = w[i];

  // ---- Phase 1: Gram over 4 DMA-staged chunks ----
  f32x4 acc[5][5];
  #pragma unroll
  for (int i = 0; i < 5; ++i)
    #pragma unroll
    for (int j = 0; j < 5; ++j) acc[i][j] = (f32x4){0.f, 0.f, 0.f, 0.f};

  for (int chunk = 0; chunk < 4; ++chunk) {
    // DMA stage: 80 KB contiguous; wave stripe = 10 KB = 10 x 1024 B.
    {
      const char* gsrc = (const char*)(xb + (size_t)chunk * 256 * NPTS);
      char* lbase = (char*)xstage;
      #pragma unroll
      for (int i = 0; i < 10; ++i) {
        const int off = (wv * 10 + i) * 1024;
        dma16(gsrc + off + lane * 16, lbase + off);
      }
    }
    __syncthreads();   // vmcnt(0) drain + barrier: staged data visible

    // fragment build: wave k-slice = 32 channels
    short8 fh[5], fl[5];
    const int cbase = wv * 32 + g * 8;
    #pragma unroll
    for (int t = 0; t < 5; ++t) {
      const int n = 16 * t + l15;
      #pragma unroll
      for (int j = 0; j < 8; ++j) {
        short hs, ls2;
        bsplit(xstage[(cbase + j) * 80 + n], hs, ls2);
        fh[t][j] = hs; fl[t][j] = ls2;
      }
    }
    __syncthreads();   // all reads done; next chunk's DMA may overwrite

    #pragma unroll
    for (int tn = 0; tn < 5; ++tn)
      #pragma unroll
      for (int tm = 0; tm < 5; ++tm) {
        acc[tn][tm] = __builtin_amdgcn_mfma_f32_16x16x32_bf16(fh[tn], fh[tm], acc[tn][tm], 0, 0, 0);
        acc[tn][tm] = __builtin_amdgcn_mfma_f32_16x16x32_bf16(fh[tn], fl[tm], acc[tn][tm], 0, 0, 0);
        acc[tn][tm] = __builtin_amdgcn_mfma_f32_16x16x32_bf16(fl[tn], fh[tm], acc[tn][tm], 0, 0, 0);
      }
  }

  __syncthreads();
  #pragma unroll
  for (int tn = 0; tn < 5; ++tn)
    #pragma unroll
    for (int tm = 0; tm < 5; ++tm)
      #pragma unroll
      for (int r = 0; r < 4; ++r)
        atomicAdd(&G[16 * tn + 4 * g + r][16 * tm + l15], acc[tn][tm][r]);
  __syncthreads();

  // ---- Phase 2: adj -> bf16 hi/lo [m][104] ----
  if (tid < 80) rn[tid] = 1.0f / fmaxf(sqrtf(G[tid][tid]), 1e-12f);
  __syncthreads();
  for (int i = tid; i < 80 * 104; i += 512) {
    const int m = i / 104;
    const int n = i - m * 104;
    float v = (n < 80) ? G[n][m] * (rn[n] * rn[m]) : 0.f;
    short hs, ls2; bsplit(v, hs, ls2);
    adjh[m][n] = hs; adjl[m][n] = ls2;
  }
  __syncthreads();

  // ---- Phase 3: h = X @ adj, fused leaky + w-reduce; DMA-staged chunks ----
  float sp[5] = {0.f, 0.f, 0.f, 0.f, 0.f};
  for (int chunk = 0; chunk < 4; ++chunk) {
    {
      const char* gsrc = (const char*)(xb + (size_t)chunk * 256 * NPTS);
      char* lbase = (char*)xstage;
      #pragma unroll
      for (int i = 0; i < 10; ++i) {
        const int off = (wv * 10 + i) * 1024;
        dma16(gsrc + off + lane * 16, lbase + off);
      }
    }
    __syncthreads();

    f32x4 hacc[2][5];
    #pragma unroll
    for (int i = 0; i < 2; ++i)
      #pragma unroll
      for (int j = 0; j < 5; ++j) hacc[i][j] = (f32x4){0.f, 0.f, 0.f, 0.f};

    for (int ksn = 0; ksn < 3; ++ksn) {
      const int nb = 32 * ksn + 8 * g;
      short8 bh[5], bl[5];
      #pragma unroll
      for (int tm = 0; tm < 5; ++tm) {
        bh[tm] = *reinterpret_cast<const short8*>(&adjh[16 * tm + l15][nb]);
        bl[tm] = *reinterpret_cast<const short8*>(&adjl[16 * tm + l15][nb]);
      }
      #pragma unroll
      for (int ct = 0; ct < 2; ++ct) {
        const int row = (wv * 2 + ct) * 16 + l15;   // channel row within chunk
        short8 ah, al;
        if (nb < 80) {
          const float* p = &xstage[row * 80 + nb];
          f32x4 va = *reinterpret_cast<const f32x4*>(p);
          f32x4 vb = *reinterpret_cast<const f32x4*>(p + 4);
          #pragma unroll
          for (int j = 0; j < 4; ++j) { short hs, ls2; bsplit(va[j], hs, ls2); ah[j] = hs; al[j] = ls2; }
          #pragma unroll
          for (int j = 0; j < 4; ++j) { short hs, ls2; bsplit(vb[j], hs, ls2); ah[4 + j] = hs; al[4 + j] = ls2; }
        } else {
          ah = (short8){0,0,0,0,0,0,0,0};
          al = (short8){0,0,0,0,0,0,0,0};
        }
        #pragma unroll
        for (int tm = 0; tm < 5; ++tm) {
          hacc[ct][tm] = __builtin_amdgcn_mfma_f32_16x16x32_bf16(ah, bh[tm], hacc[ct][tm], 0, 0, 0);
          hacc[ct][tm] = __builtin_amdgcn_mfma_f32_16x16x32_bf16(ah, bl[tm], hacc[ct][tm], 0, 0, 0);
          hacc[ct][tm] = __builtin_amdgcn_mfma_f32_16x16x32_bf16(al, bh[tm], hacc[ct][tm], 0, 0, 0);
        }
      }
    }

    // fused leaky + w-reduce for this chunk's rows
    #pragma unroll
    for (int ct = 0; ct < 2; ++ct) {
      const int cb = chunk * 256 + (wv * 2 + ct) * 16 + 4 * g;
      #pragma unroll
      for (int r = 0; r < 4; ++r) {
        const float wc = wl[cb + r];
        #pragma unroll
        for (int tm = 0; tm < 5; ++tm) sp[tm] += leaky(hacc[ct][tm][r]) * wc;
      }
    }
    __syncthreads();   // xstage reads done; next chunk DMA safe
  }

  #pragma unroll
  for (int tm = 0; tm < 5; ++tm) {
    float v = sp[tm];
    v += __shfl_xor(v, 16);
    v += __shfl_xor(v, 32);
    if (g == 0) atomicAdd(&ssc[16 * tm + l15], v);
  }
  __syncthreads();

  // ---- Phase 4: softmax (wave 0) -> attn to global ws ----
  if (wv == 0) {
    const float b0 = bias[0];
    float v0 = leaky(ssc[lane] + b0) * INVTEMP;
    float v1 = -3.0e38f;
    if (lane < 16) v1 = leaky(ssc[64 + lane] + b0) * INVTEMP;
    float mx = fmaxf(v0, v1);
    #pragma unroll
    for (int off = 32; off >= 1; off >>= 1) mx = fmaxf(mx, __shfl_xor(mx, off));
    float e0 = expf(v0 - mx);
    float e1 = (lane < 16) ? expf(v1 - mx) : 0.f;
    float sum = e0 + e1;
    #pragma unroll
    for (int off = 32; off >= 1; off >>= 1) sum += __shfl_xor(sum, off);
    const float inv = 1.0f / sum;
    attn_ws[b * 80 + lane] = e0 * inv + 1.0f;
    if (lane < 16) attn_ws[b * 80 + 64 + lane] = e1 * inv + 1.0f;
  }
}

// Scale kernel: out = x * attn[n]. grid = 256 batches x 8 chunks, 256 thr,
// full occupancy streaming (8 blocks/CU).
__launch_bounds__(256)
__global__ void scgcn_scale_kernel(const float* __restrict__ x,
                                   const float* __restrict__ attn_ws,
                                   float* __restrict__ out) {
  __shared__ f32x4 attnv[20];
  const int tid   = threadIdx.x;
  const int b     = blockIdx.x >> 3;
  const int chunk = blockIdx.x & 7;

  if (tid < 20) attnv[tid] = reinterpret_cast<const f32x4*>(attn_ws + b * 80)[tid];
  __syncthreads();

  const f32x4* __restrict__ xv = reinterpret_cast<const f32x4*>(x + (size_t)b * (CH * NPTS));
  f32x4* __restrict__ ov = reinterpret_cast<f32x4*>(out + (size_t)b * (CH * NPTS));
  #pragma unroll
  for (int k = 0; k < 10; ++k) {
    const int e4 = chunk * 2560 + k * 256 + tid;   // f32x4 index within batch
    f32x4 v = xv[e4];
    f32x4 a = attnv[e4 % 20];
    v[0] *= a[0]; v[1] *= a[1]; v[2] *= a[2]; v[3] *= a[3];
    ov[e4] = v;
  }
}

extern "C" void kernel_launch(void* const* d_in, const int* in_sizes, int n_in,
                              void* d_out, int out_size, void* d_ws, size_t ws_size,
                              hipStream_t stream) {
  const float* x    = (const float*)d_in[0];
  const float* w    = (const float*)d_in[1];
  const float* bias = (const float*)d_in[2];
  float* out        = (float*)d_out;
  float* attn_ws    = (float*)d_ws;    // 256*80 f32 = 80 KB

  scgcn_main_kernel<<<256, 512, 0, stream>>>(x, w, bias, attn_ws);
  scgcn_scale_kernel<<<256 * 8, 256, 0, stream>>>(x, attn_ws, out);
}